// Round 9
// baseline (157.279 us; speedup 1.0000x reference)
//
#include <hip/hip_runtime.h>
#include <math.h>

typedef __attribute__((ext_vector_type(8))) short bf16x8;
typedef __attribute__((ext_vector_type(4))) float f32x4;
typedef __attribute__((ext_vector_type(4))) int int4v;

#define GL_LDS16(g, l) __builtin_amdgcn_global_load_lds( \
    (const __attribute__((address_space(1))) void*)(g), \
    (__attribute__((address_space(3))) void*)(l), 16, 0, 0)

__device__ __forceinline__ ushort f2bf(float f) {
    union { float f; unsigned u; } v; v.f = f;
    unsigned r = (v.u + 0x7fffu + ((v.u >> 16) & 1u)) >> 16;
    return (ushort)r;
}
__device__ __forceinline__ float bf2f(ushort h) {
    union { unsigned u; float f; } v; v.u = ((unsigned)h) << 16;
    return v.f;
}

// ---------------------------------------------------------------------------
// Weight prepack helper: w[oc][cin][3][3] -> wp[cc][kk][kg][CoutP][8]
__device__ __forceinline__ void prep_one(const float* __restrict__ w,
        ushort* __restrict__ wp, int u, int Cin, int CoutR, int CoutP) {
    int oc = u % CoutP; int t = u / CoutP;
    int kg = t & 3; t >>= 2;
    int kk = t % 9; int cc = t / 9;
    alignas(16) ushort tmp[8];
    for (int j = 0; j < 8; ++j) {
        int c = cc * 32 + kg * 8 + j;
        float v = (oc < CoutR) ? w[((size_t)oc * Cin + c) * 9 + kk] : 0.f;
        tmp[j] = f2bf(v);
    }
    *(int4v*)(wp + (size_t)u * 8) = *(int4v*)tmp;
}

// ---------------------------------------------------------------------------
// Fused packs + prepack:
//  z=0: pack concat(src0,src1)->xin1[px][128]  AND xg1[b][g][px][8] (src0 groups)
//  z=1: up2(l_off)*2 -> xin2[px][64:128]; z=2: up2(l_fea) -> xin4[px][64:128]
//  z=3: all weight prepacks + om bias permute + zero guard
__global__ __launch_bounds__(256) void pack_combo_k(
        const float* __restrict__ s0, const float* __restrict__ s1,
        const float* __restrict__ lo, const float* __restrict__ lf,
        const float* __restrict__ w1, const float* __restrict__ w2,
        const float* __restrict__ w3, const float* __restrict__ wom,
        const float* __restrict__ wd, const float* __restrict__ wf,
        const float* __restrict__ bom,
        ushort* __restrict__ xin1, ushort* __restrict__ xin2,
        ushort* __restrict__ xin4, ushort* __restrict__ xg1,
        ushort* __restrict__ w1p, ushort* __restrict__ w2p,
        ushort* __restrict__ w3p, ushort* __restrict__ womp,
        ushort* __restrict__ wdp, ushort* __restrict__ wfp,
        float* __restrict__ bpp, float* __restrict__ zg) {
    int b = blockIdx.y;
    int z = blockIdx.z;
    int px = blockIdx.x * 64 + (threadIdx.x & 63);
    int u = threadIdx.x >> 6;
    if (z == 0) {
        for (int half = 0; half < 2; ++half) {
            int cg = u + half * 4;
            alignas(16) ushort tmp[16];
            for (int i = 0; i < 16; ++i) {
                int c = cg * 16 + i;
                float v = (c < 64) ? s0[((size_t)(b * 64 + c)) * 9216 + px]
                                   : s1[((size_t)(b * 64 + c - 64)) * 9216 + px];
                tmp[i] = f2bf(v);
            }
            ushort* dst = xin1 + ((size_t)(b * 9216) + px) * 128 + cg * 16;
            *(int4v*)dst = *(int4v*)&tmp[0];
            *(int4v*)(dst + 8) = *(int4v*)&tmp[8];
            if (half == 0) {
                // gather copy: groups g = cg*2, cg*2+1
                ushort* gdst = xg1 + (((size_t)(b * 8 + cg * 2) * 9216) + px) * 8;
                *(int4v*)gdst = *(int4v*)&tmp[0];
                *(int4v*)(gdst + 9216 * 8) = *(int4v*)&tmp[8];
            }
        }
    } else if (z < 3) {
        const float* in = (z == 1) ? lo : lf;
        float scale = (z == 1) ? 2.0f : 1.0f;
        ushort* xo = (z == 1) ? xin2 : xin4;
        int y = px / 96, x = px % 96;
        float sy = fmaxf(y * 0.5f - 0.25f, 0.f);
        float sx = fmaxf(x * 0.5f - 0.25f, 0.f);
        int y0 = (int)sy, x0 = (int)sx;
        float ty = sy - (float)y0, tx = sx - (float)x0;
        int y1 = min(y0 + 1, 47), x1 = min(x0 + 1, 47);
        alignas(16) ushort tmp[16];
        for (int i = 0; i < 16; ++i) {
            int c = u * 16 + i;
            const float* p = in + ((size_t)(b * 64 + c)) * 2304;
            float v00 = p[y0 * 48 + x0], v01 = p[y0 * 48 + x1];
            float v10 = p[y1 * 48 + x0], v11 = p[y1 * 48 + x1];
            float v = (v00 * (1.f - tx) + v01 * tx) * (1.f - ty)
                    + (v10 * (1.f - tx) + v11 * tx) * ty;
            tmp[i] = f2bf(v * scale);
        }
        ushort* dst = xo + ((size_t)(b * 9216) + px) * 128 + 64 + u * 16;
        *(int4v*)dst = *(int4v*)&tmp[0];
        *(int4v*)(dst + 8) = *(int4v*)&tmp[8];
    } else {
        // prepack: 60240 units over 576 blocks
        int uu = (blockIdx.x + 144 * blockIdx.y) * 256 + threadIdx.x;
        if (uu < 9216) prep_one(w1, w1p, uu, 128, 64, 64);
        else if (uu < 18432) prep_one(w2, w2p, uu - 9216, 128, 64, 64);
        else if (uu < 23040) prep_one(w3, w3p, uu - 18432, 64, 64, 64);
        else if (uu < 46080) {
            // om conv, permuted+padded: CoutP=320, oc p = gkk*4 + t3
            int v = uu - 23040;
            int ocp = v % 320; int t = v / 320;
            int kg = t & 3; t >>= 2;
            int kk = t % 9; int cc = t / 9;
            int t3 = ocp & 3, gkkp = ocp >> 2;
            alignas(16) ushort tmp[8];
            for (int j = 0; j < 8; ++j) {
                int c = cc * 32 + kg * 8 + j;
                float vv = (t3 < 3 && gkkp < 72)
                    ? wom[((size_t)(t3 * 72 + gkkp) * 64 + c) * 9 + kk] : 0.f;
                tmp[j] = f2bf(vv);
            }
            *(int4v*)(womp + (size_t)v * 8) = *(int4v*)tmp;
        } else if (uu < 50688) {
            int v = uu - 46080;               // [gkk*64 + oc][8], k=(g*9+kk)*8+cg
            int oc = v & 63; int gkk = v >> 6;
            int g = gkk / 9, kk = gkk % 9;
            alignas(16) ushort tmp[8];
            for (int j = 0; j < 8; ++j)
                tmp[j] = f2bf(wd[((size_t)oc * 64 + g * 8 + j) * 9 + kk]);
            *(int4v*)(wdp + (size_t)v * 8) = *(int4v*)tmp;
        } else if (uu < 59904) prep_one(wf, wfp, uu - 50688, 128, 64, 64);
        else if (uu < 60224) {
            int ocp = uu - 59904; int t3 = ocp & 3, gkkp = ocp >> 2;
            bpp[ocp] = (t3 < 3 && gkkp < 72) ? bom[t3 * 72 + gkkp] : 0.f;
        } else if (uu < 60240) zg[uu - 60224] = 0.f;  // 64-B zero guard
    }
}

// ---------------------------------------------------------------------------
// MFMA 3x3 conv: per-wave MT*16 oc x 16 px, block = 8x8 px tile.
// MT=4/NZ=1 for 64-out convs: ONE block per px tile (no duplicate staging),
// each wave computes the full 64 oc for its 16 px (72 MFMA/wave @ CIN=128).
// Activation staged in 64-channel slices via global_load_lds; zero-guard for
// pad/OOB. CIN=64: single stage (one barrier). CIN=128: 2 slices dbuf.
// A-fragments read directly from global prepacked weights (L1-hot).
template<int CIN, int MT, int NZ, bool LRELU, bool ST_F32, bool ST_CHL>
__global__ __launch_bounds__(256, 4) void conv_mfma_k(
        const ushort* __restrict__ xin,      // [b][9216][CIN] bf16
        const ushort* __restrict__ wp,       // [CIN/32][9][4][CoutP][8]
        const float* __restrict__ bias,
        float* __restrict__ outf,            // NCHW fp32
        ushort* __restrict__ chl,            // ch-last bf16
        const ushort* __restrict__ zg,       // 64-B zero guard
        int CoutR, int CoutP, int ochs, int ocoff) {
    constexpr int SL = CIN / 64;
    constexpr int OCN = MT * 16;
    __shared__ ushort s_act[SL][7200];        // [buf][100 rows x 72u] 14.4 KB each

    int tid = threadIdx.x;
    int wv = tid >> 6, ln = tid & 63;
    int l15 = ln & 15, l4 = ln >> 4;

    constexpr int TOTAL = 144 * 4 * NZ;
    constexpr int CHUNK = TOTAL / 8;
    int bid = blockIdx.x;
    int nid = (bid & 7) * CHUNK + (bid >> 3);
    int zc = nid % NZ; int r1 = nid / NZ;
    int tile = r1 % 144; int b = r1 / 144;    // b-major banding
    int bx = (tile % 12) * 8, by = (tile / 12) * 8;
    int oc0 = zc * OCN;

    int px_l = wv * 16 + l15;                 // px in 8x8 tile
    int py = px_l >> 3, pxx = px_l & 7;
    int b_base = (py * 10 + pxx) * 72 + l4 * 8;

    const ushort* wlane = wp + ((size_t)l4 * CoutP + oc0 + l15) * 8;

    f32x4 acc[MT];
#pragma unroll
    for (int mt = 0; mt < MT; ++mt) acc[mt] = (f32x4){0.f, 0.f, 0.f, 0.f};

    auto STAGE = [&](int sl, int buf) {
        for (int i = tid; i < 900; i += 256) {
            int p = i / 9, q = i - p * 9;     // q==8 -> pad slot
            int gy = by + (p / 10) - 1, gx = bx + (p % 10) - 1;
            const ushort* src = zg;
            if (q < 8 && (unsigned)gy < 96u && (unsigned)gx < 96u)
                src = xin + ((size_t)(b * 9216 + gy * 96 + gx) * CIN
                             + sl * 64 + q * 8);
            GL_LDS16(src, s_act[buf] + (size_t)i * 8);
        }
    };

    STAGE(0, 0);
    __syncthreads();
#pragma unroll
    for (int sl = 0; sl < SL; ++sl) {
        if (sl + 1 < SL) STAGE(sl + 1, (sl + 1) & 1);
#pragma unroll
        for (int cc2 = 0; cc2 < 2; ++cc2) {
#pragma unroll
            for (int kk = 0; kk < 9; ++kk) {
                bf16x8 bfrag = *(const bf16x8*)(s_act[sl & (SL - 1)] + b_base +
                                   ((kk / 3) * 10 + (kk % 3)) * 72 + cc2 * 32);
#pragma unroll
                for (int mt = 0; mt < MT; ++mt) {
                    bf16x8 af = *(const bf16x8*)(wlane +
                        ((size_t)((sl * 2 + cc2) * 36 + kk * 4) * CoutP + mt * 16) * 8);
                    acc[mt] = __builtin_amdgcn_mfma_f32_16x16x32_bf16(
                        af, bfrag, acc[mt], 0, 0, 0);
                }
            }
        }
        if (sl + 1 < SL) __syncthreads();
    }

    int gy = by + py, gx = bx + pxx;
    size_t pxg = (size_t)b * 9216 + gy * 96 + gx;
#pragma unroll
    for (int mt = 0; mt < MT; ++mt) {
        int ocb = oc0 + mt * 16 + l4 * 4;
        ushort hb[4];
#pragma unroll
        for (int r = 0; r < 4; ++r) {
            int oc = ocb + r;
            float v = acc[mt][r] + ((oc < CoutR) ? bias[oc] : 0.f);
            if (LRELU) v = (v >= 0.f) ? v : 0.1f * v;
            hb[r] = f2bf(v);
            if (ST_F32 && oc < CoutR)
                outf[((size_t)b * CoutR + oc) * 9216 + gy * 96 + gx] = v;
        }
        if (ST_CHL && ocb < CoutR) {
            uint2 pk;
            pk.x = (uint)hb[0] | ((uint)hb[1] << 16);
            pk.y = (uint)hb[2] | ((uint)hb[3] << 16);
            *(uint2*)(chl + pxg * ochs + ocoff + ocb) = pk;
        }
    }
}

// ---------------------------------------------------------------------------
// Fused DCNv2: gather-layout xg1 [b][g][px][8] (x-corners adjacent -> paired
// 16B loads, line-coalesced across lanes), split-K(2), interleaved om,
// distance-1 software-pipelined PREP. grid = 2304 x 128 thr.
__global__ __launch_bounds__(128, 4) void dcn_fused_k(
        const ushort* __restrict__ xg1,      // [b][8][9216][8] bf16
        const ushort* __restrict__ om,       // [b][px][288] interleaved bf16
        const ushort* __restrict__ wdp,
        const float* __restrict__ bd, ushort* __restrict__ chl) {
    __shared__ float s_red[64][17];
    int tid = threadIdx.x;
    int kq = tid >> 6, ln = tid & 63;
    int l15 = ln & 15, l4 = ln >> 4;
    int bid = blockIdx.x;                     // 0..2303
    int nid = (bid & 7) * 288 + (bid >> 3);   // XCD-chunked swizzle
    int pxb = nid % 576; int b = nid / 576;   // b-major banding
    int px = pxb * 16 + l15;
    int y = px / 96, xx = px % 96;

    f32x4 acc[4];
#pragma unroll
    for (int mt = 0; mt < 4; ++mt) acc[mt] = (f32x4){0.f, 0.f, 0.f, 0.f};
    const ushort* omp_ = om + ((size_t)b * 9216 + px) * 288 + kq * 144;

    // hoist the 9 om quads (oy,ox,ml,pad): one latency wait total
    uint2 ovv[9];
#pragma unroll
    for (int s = 0; s < 9; ++s)
        ovv[s] = *(const uint2*)(omp_ + s * 16 + l4 * 4);

    int4v Abuf[2][4];
    float cwbuf[2][4];

    auto PREP = [&](int s, int4v* A, float* cw) {
        int gkk = kq * 36 + s * 4 + l4;
        int g = gkk / 9, kk = gkk - g * 9;
        union { uint2 u; ushort us[4]; } ov; ov.u = ovv[s];
        float oy = bf2f(ov.us[0]), ox = bf2f(ov.us[1]);
        float mm = 1.f / (1.f + __expf(-bf2f(ov.us[2])));
        float py = oy + (float)(y + kk / 3 - 1);
        float pxf = ox + (float)(xx + kk % 3 - 1);
        float yf = floorf(py), xf = floorf(pxf);
        float fy = py - yf, fx = pxf - xf;
        int iy0 = (int)yf, ix0 = (int)xf;
        int iy1 = iy0 + 1, ix1 = ix0 + 1;
        float vy0 = ((unsigned)iy0 < 96u) ? 1.f : 0.f;
        float vy1 = ((unsigned)iy1 < 96u) ? 1.f : 0.f;
        float vx0 = ((unsigned)ix0 < 96u) ? 1.f : 0.f;
        float vx1 = ((unsigned)ix1 < 96u) ? 1.f : 0.f;
        int r0 = min(max(iy0, 0), 95), r1 = min(max(iy1, 0), 95);
        int lb = min(max(ix0, 0), 94);
        // half-selects: which 16B cell (lb or lb+1) each x-corner lives in
        float h0 = (float)min(max(ix0 - lb, 0), 1);   // 1 only when ix0==95
        float h1 = (float)min(max(ix1 - lb, 0), 1);   // 0 only when ix0==-1
        float wx0 = (1.f - fx) * vx0, wx1 = fx * vx1;
        float xw0 = wx0 * (1.f - h0) + wx1 * (1.f - h1);
        float xw1 = wx0 * h0 + wx1 * h1;
        float rw0 = (1.f - fy) * vy0 * mm, rw1 = fy * vy1 * mm;
        cw[0] = rw0 * xw0; cw[1] = rw0 * xw1;
        cw[2] = rw1 * xw0; cw[3] = rw1 * xw1;
        const ushort* gp = xg1 + ((size_t)(b * 8 + g) * 9216) * 8;
        const ushort* p0 = gp + ((size_t)(r0 * 96 + lb)) * 8;
        const ushort* p1 = gp + ((size_t)(r1 * 96 + lb)) * 8;
        A[0] = *(const int4v*)p0;
        A[1] = *(const int4v*)(p0 + 8);
        A[2] = *(const int4v*)p1;
        A[3] = *(const int4v*)(p1 + 8);
    };

    PREP(0, Abuf[0], cwbuf[0]);
#pragma unroll
    for (int s = 0; s < 9; ++s) {
        if (s + 1 < 9) PREP(s + 1, Abuf[(s + 1) & 1], cwbuf[(s + 1) & 1]);
        const int4v* A = Abuf[s & 1];
        const float* cw = cwbuf[s & 1];
        union { int4v v; ushort us[8]; } a0, a1, b0, b1;
        a0.v = A[0]; a1.v = A[1]; b0.v = A[2]; b1.v = A[3];
        union { ushort us[8]; bf16x8 v; } bu;
#pragma unroll
        for (int j = 0; j < 8; ++j) {
            float v = cw[0] * bf2f(a0.us[j]) + cw[1] * bf2f(a1.us[j]) +
                      cw[2] * bf2f(b0.us[j]) + cw[3] * bf2f(b1.us[j]);
            bu.us[j] = f2bf(v);
        }
        int gkk = kq * 36 + s * 4 + l4;
#pragma unroll
        for (int mt = 0; mt < 4; ++mt) {
            bf16x8 af = *(const bf16x8*)(wdp +
                ((size_t)gkk * 64 + mt * 16 + l15) * 8);
            acc[mt] = __builtin_amdgcn_mfma_f32_16x16x32_bf16(
                af, bu.v, acc[mt], 0, 0, 0);
        }
    }

    // split-K reduce: kq=1 writes, kq=0 adds + stores
    if (kq) {
#pragma unroll
        for (int mt = 0; mt < 4; ++mt)
#pragma unroll
            for (int r = 0; r < 4; ++r)
                s_red[ln][mt * 4 + r] = acc[mt][r];
    }
    __syncthreads();
    if (!kq) {
        size_t pb = (size_t)b * 9216 + px;
#pragma unroll
        for (int mt = 0; mt < 4; ++mt) {
            ushort hb[4];
#pragma unroll
            for (int r = 0; r < 4; ++r) {
                int oc = mt * 16 + l4 * 4 + r;
                float v = acc[mt][r] + s_red[ln][mt * 4 + r] + bd[oc];
                hb[r] = f2bf(v);
            }
            uint2 pk;
            pk.x = (uint)hb[0] | ((uint)hb[1] << 16);
            pk.y = (uint)hb[2] | ((uint)hb[3] << 16);
            *(uint2*)(chl + pb * 128 + mt * 16 + l4 * 4) = pk;
        }
    }
}

// ---------------------------------------------------------------------------
extern "C" void kernel_launch(void* const* d_in, const int* in_sizes, int n_in,
                              void* d_out, int out_size, void* d_ws, size_t ws_size,
                              hipStream_t stream) {
    const float* src0  = (const float*)d_in[0];
    const float* src1  = (const float*)d_in[1];
    const float* l_off = (const float*)d_in[2];
    const float* l_fea = (const float*)d_in[3];
    const float* w1 = (const float*)d_in[4];   const float* b1 = (const float*)d_in[5];
    const float* w2 = (const float*)d_in[6];   const float* b2 = (const float*)d_in[7];
    const float* w3 = (const float*)d_in[8];   const float* b3 = (const float*)d_in[9];
    const float* wom = (const float*)d_in[10]; const float* bom = (const float*)d_in[11];
    const float* wd = (const float*)d_in[12];  const float* bd = (const float*)d_in[13];
    const float* wf = (const float*)d_in[14];  const float* bf = (const float*)d_in[15];

    // workspace schedule (lifetimes annotated; regions reused after death)
    char* W = (char*)d_ws;
    ushort* xin1 = (ushort*)(W + 0);          //  9,437,184 B  live to conv1
    ushort* xin2 = (ushort*)(W + 9437184);    //  9,437,184 B  dead after conv2
    ushort* xoff = (ushort*)(W + 9437184);    //  4,718,592 B  over xin2 (dead)
    ushort* xin3 = (ushort*)(W + 18874368);   //  4,718,592 B  dead after conv3
    ushort* omb  = (ushort*)(W + 23592960);   // 21,233,664 B  [b][px][288]
    ushort* xin4 = (ushort*)(W + 44826624);   //  9,437,184 B  [b][px][128]
    ushort* xg1  = (ushort*)(W + 54263808);   //  4,718,592 B  [b][8][px][8]
    ushort* w1p  = (ushort*)(W + 58982400);   // 147,456 B
    ushort* w2p  = (ushort*)(W + 59129856);   // 147,456 B
    ushort* w3p  = (ushort*)(W + 59277312);   //  73,728 B
    ushort* womp = (ushort*)(W + 59351040);   // 368,640 B (320-wide permuted)
    ushort* wdp  = (ushort*)(W + 59719680);   //  73,728 B
    ushort* wfp  = (ushort*)(W + 59793408);   // 147,456 B
    float*  bpp  = (float*)(W + 59940864);    //   1,280 B permuted om bias
    float*  zgrd = (float*)(W + 59942144);    //      64 B zero guard -> 57.2 MB

    float* out_off = (float*)d_out;
    float* out_fea = out_off + (size_t)4 * 64 * 9216;

    // fused packs + prepack (z=3)
    pack_combo_k<<<dim3(144, 4, 4), 256, 0, stream>>>(
        src0, src1, l_off, l_fea, w1, w2, w3, wom, wd, wf, bom,
        xin1, xin2, xin4, xg1, w1p, w2p, w3p, womp, wdp, wfp, bpp, zgrd);

    const ushort* zg = (const ushort*)zgrd;
    // conv1: xin1 -> xin2[0:64] (lrelu, ch-last)  MT=4/NZ=1: single-stage tiles
    conv_mfma_k<128, 4, 1, true, false, true><<<576, 256, 0, stream>>>(
        xin1, w1p, b1, nullptr, xin2, zg, 64, 64, 128, 0);
    // conv2: xin2 -> xin3 (lrelu, ch-last)
    conv_mfma_k<128, 4, 1, true, false, true><<<576, 256, 0, stream>>>(
        xin2, w2p, b2, nullptr, xin3, zg, 64, 64, 64, 0);
    // conv3: xin3 -> out_off (fp32 NCHW) + xoff (ch-last)
    conv_mfma_k<64, 4, 1, true, true, true><<<576, 256, 0, stream>>>(
        xin3, w3p, b3, out_off, xoff, zg, 64, 64, 64, 0);
    // om conv: xoff -> omb interleaved [px][288] (permuted weights/bias, MT=4)
    conv_mfma_k<64, 4, 5, false, false, true><<<2880, 256, 0, stream>>>(
        xoff, womp, bpp, nullptr, omb, zg, 288, 320, 288, 0);
    // fused DCN -> xin4[0:64]  (samples xg1, reads omb interleaved)
    dcn_fused_k<<<2304, 128, 0, stream>>>(xg1, omb, wdp, bd, xin4);
    // fea conv: xin4 -> out_fea (fp32 NCHW, lrelu)
    conv_mfma_k<128, 4, 1, true, true, false><<<576, 256, 0, stream>>>(
        xin4, wfp, bf, out_fea, nullptr, zg, 64, 64, 0, 0);
}

// Round 10
// 145.133 us; speedup vs baseline: 1.0837x; 1.0837x over previous
//
#include <hip/hip_runtime.h>
#include <hip/hip_fp16.h>
#include <math.h>

typedef __attribute__((ext_vector_type(8))) short bf16x8;
typedef __attribute__((ext_vector_type(8))) _Float16 half8;
typedef __attribute__((ext_vector_type(4))) float f32x4;
typedef __attribute__((ext_vector_type(4))) int int4v;

#define GL_LDS16(g, l) __builtin_amdgcn_global_load_lds( \
    (const __attribute__((address_space(1))) void*)(g), \
    (__attribute__((address_space(3))) void*)(l), 16, 0, 0)

__device__ __forceinline__ ushort f2bf(float f) {
    union { float f; unsigned u; } v; v.f = f;
    unsigned r = (v.u + 0x7fffu + ((v.u >> 16) & 1u)) >> 16;
    return (ushort)r;
}
__device__ __forceinline__ float bf2f(ushort h) {
    union { unsigned u; float f; } v; v.u = ((unsigned)h) << 16;
    return v.f;
}

// ---------------------------------------------------------------------------
// Weight prepack helper: w[oc][cin][3][3] -> wp[cc][kk][kg][CoutP][8]
__device__ __forceinline__ void prep_one(const float* __restrict__ w,
        ushort* __restrict__ wp, int u, int Cin, int CoutR, int CoutP) {
    int oc = u % CoutP; int t = u / CoutP;
    int kg = t & 3; t >>= 2;
    int kk = t % 9; int cc = t / 9;
    alignas(16) ushort tmp[8];
    for (int j = 0; j < 8; ++j) {
        int c = cc * 32 + kg * 8 + j;
        float v = (oc < CoutR) ? w[((size_t)oc * Cin + c) * 9 + kk] : 0.f;
        tmp[j] = f2bf(v);
    }
    *(int4v*)(wp + (size_t)u * 8) = *(int4v*)tmp;
}

// ---------------------------------------------------------------------------
// Fused packs + prepack:
//  z=0: pack concat(src0,src1)->xin1[px][128] (bf16) AND xg1[b][g][px][8] (f16)
//  z=1: up2(l_off)*2 -> xin2[px][64:128]; z=2: up2(l_fea) -> xin4[px][64:128]
//  z=3: all weight prepacks (wd -> f16) + om bias permute + zero guard
__global__ __launch_bounds__(256) void pack_combo_k(
        const float* __restrict__ s0, const float* __restrict__ s1,
        const float* __restrict__ lo, const float* __restrict__ lf,
        const float* __restrict__ w1, const float* __restrict__ w2,
        const float* __restrict__ w3, const float* __restrict__ wom,
        const float* __restrict__ wd, const float* __restrict__ wf,
        const float* __restrict__ bom,
        ushort* __restrict__ xin1, ushort* __restrict__ xin2,
        ushort* __restrict__ xin4, ushort* __restrict__ xg1,
        ushort* __restrict__ w1p, ushort* __restrict__ w2p,
        ushort* __restrict__ w3p, ushort* __restrict__ womp,
        ushort* __restrict__ wdp, ushort* __restrict__ wfp,
        float* __restrict__ bpp, float* __restrict__ zg) {
    int b = blockIdx.y;
    int z = blockIdx.z;
    int px = blockIdx.x * 64 + (threadIdx.x & 63);
    int u = threadIdx.x >> 6;
    if (z == 0) {
        for (int half = 0; half < 2; ++half) {
            int cg = u + half * 4;
            float vals[16];
            alignas(16) ushort tmp[16];
            for (int i = 0; i < 16; ++i) {
                int c = cg * 16 + i;
                float v = (c < 64) ? s0[((size_t)(b * 64 + c)) * 9216 + px]
                                   : s1[((size_t)(b * 64 + c - 64)) * 9216 + px];
                vals[i] = v;
                tmp[i] = f2bf(v);
            }
            ushort* dst = xin1 + ((size_t)(b * 9216) + px) * 128 + cg * 16;
            *(int4v*)dst = *(int4v*)&tmp[0];
            *(int4v*)(dst + 8) = *(int4v*)&tmp[8];
            if (half == 0) {
                // gather copy in f16: groups g = cg*2, cg*2+1
                alignas(16) __half th[16];
                for (int i = 0; i < 16; ++i) th[i] = __float2half(vals[i]);
                ushort* gdst = xg1 + (((size_t)(b * 8 + cg * 2) * 9216) + px) * 8;
                *(int4v*)gdst = *(int4v*)&th[0];
                *(int4v*)(gdst + 9216 * 8) = *(int4v*)&th[8];
            }
        }
    } else if (z < 3) {
        const float* in = (z == 1) ? lo : lf;
        float scale = (z == 1) ? 2.0f : 1.0f;
        ushort* xo = (z == 1) ? xin2 : xin4;
        int y = px / 96, x = px % 96;
        float sy = fmaxf(y * 0.5f - 0.25f, 0.f);
        float sx = fmaxf(x * 0.5f - 0.25f, 0.f);
        int y0 = (int)sy, x0 = (int)sx;
        float ty = sy - (float)y0, tx = sx - (float)x0;
        int y1 = min(y0 + 1, 47), x1 = min(x0 + 1, 47);
        alignas(16) ushort tmp[16];
        for (int i = 0; i < 16; ++i) {
            int c = u * 16 + i;
            const float* p = in + ((size_t)(b * 64 + c)) * 2304;
            float v00 = p[y0 * 48 + x0], v01 = p[y0 * 48 + x1];
            float v10 = p[y1 * 48 + x0], v11 = p[y1 * 48 + x1];
            float v = (v00 * (1.f - tx) + v01 * tx) * (1.f - ty)
                    + (v10 * (1.f - tx) + v11 * tx) * ty;
            tmp[i] = f2bf(v * scale);
        }
        ushort* dst = xo + ((size_t)(b * 9216) + px) * 128 + 64 + u * 16;
        *(int4v*)dst = *(int4v*)&tmp[0];
        *(int4v*)(dst + 8) = *(int4v*)&tmp[8];
    } else {
        // prepack: 57904 units over 576 blocks
        int uu = (blockIdx.x + 144 * blockIdx.y) * 256 + threadIdx.x;
        if (uu < 9216) prep_one(w1, w1p, uu, 128, 64, 64);
        else if (uu < 18432) prep_one(w2, w2p, uu - 9216, 128, 64, 64);
        else if (uu < 23040) prep_one(w3, w3p, uu - 18432, 64, 64, 64);
        else if (uu < 43776) {
            // om conv, permuted: CoutP=288, oc p = gkk*4 + t3 (t3==3 -> pad)
            int v = uu - 23040;               // units = 2*9*4*288 = 20736
            int ocp = v % 288; int t = v / 288;
            int kg = t & 3; t >>= 2;
            int kk = t % 9; int cc = t / 9;
            int t3 = ocp & 3, gkkp = ocp >> 2;
            alignas(16) ushort tmp[8];
            for (int j = 0; j < 8; ++j) {
                int c = cc * 32 + kg * 8 + j;
                float vv = (t3 < 3)
                    ? wom[((size_t)(t3 * 72 + gkkp) * 64 + c) * 9 + kk] : 0.f;
                tmp[j] = f2bf(vv);
            }
            *(int4v*)(womp + (size_t)v * 8) = *(int4v*)tmp;
        } else if (uu < 48384) {
            int v = uu - 43776;               // wd -> f16 [gkk*64 + oc][8]
            int oc = v & 63; int gkk = v >> 6;
            int g = gkk / 9, kk = gkk % 9;
            alignas(16) __half tmp[8];
            for (int j = 0; j < 8; ++j)
                tmp[j] = __float2half(wd[((size_t)oc * 64 + g * 8 + j) * 9 + kk]);
            *(int4v*)(wdp + (size_t)v * 8) = *(int4v*)tmp;
        } else if (uu < 57600) prep_one(wf, wfp, uu - 48384, 128, 64, 64);
        else if (uu < 57888) {
            int ocp = uu - 57600; int t3 = ocp & 3, gkkp = ocp >> 2;
            bpp[ocp] = (t3 < 3) ? bom[t3 * 72 + gkkp] : 0.f;
        } else if (uu < 57904) zg[uu - 57888] = 0.f;  // 64-B zero guard
    }
}

// ---------------------------------------------------------------------------
// MFMA 3x3 conv: per-wave MT*16 oc x 16 px, block = 8x8 px tile.
// Activation staged in 64-channel slices via global_load_lds; zero-guard for
// pad/OOB. CIN=64: single stage (one barrier). CIN=128: 2 slices dbuf.
// A-fragments read directly from global prepacked weights (L1-hot).
template<int CIN, int MT, int NZ, bool LRELU, bool ST_F32, bool ST_CHL>
__global__ __launch_bounds__(256, 4) void conv_mfma_k(
        const ushort* __restrict__ xin,      // [b][9216][CIN] bf16
        const ushort* __restrict__ wp,       // [CIN/32][9][4][CoutP][8]
        const float* __restrict__ bias,
        float* __restrict__ outf,            // NCHW fp32
        ushort* __restrict__ chl,            // ch-last bf16
        const ushort* __restrict__ zg,       // 64-B zero guard
        int CoutR, int CoutP, int ochs, int ocoff) {
    constexpr int SL = CIN / 64;
    constexpr int OCN = MT * 16;
    __shared__ ushort s_act[SL][7200];        // [buf][100 rows x 72u] 14.4 KB each

    int tid = threadIdx.x;
    int wv = tid >> 6, ln = tid & 63;
    int l15 = ln & 15, l4 = ln >> 4;

    constexpr int TOTAL = 144 * 4 * NZ;
    constexpr int CHUNK = TOTAL / 8;
    int bid = blockIdx.x;
    int nid = (bid & 7) * CHUNK + (bid >> 3);
    int zc = nid % NZ; int r1 = nid / NZ;
    int tile = r1 % 144; int b = r1 / 144;    // b-major banding
    int bx = (tile % 12) * 8, by = (tile / 12) * 8;
    int oc0 = zc * OCN;

    int px_l = wv * 16 + l15;                 // px in 8x8 tile
    int py = px_l >> 3, pxx = px_l & 7;
    int b_base = (py * 10 + pxx) * 72 + l4 * 8;

    const ushort* wlane = wp + ((size_t)l4 * CoutP + oc0 + l15) * 8;

    f32x4 acc[MT];
#pragma unroll
    for (int mt = 0; mt < MT; ++mt) acc[mt] = (f32x4){0.f, 0.f, 0.f, 0.f};

    auto STAGE = [&](int sl, int buf) {
        for (int i = tid; i < 900; i += 256) {
            int p = i / 9, q = i - p * 9;     // q==8 -> pad slot
            int gy = by + (p / 10) - 1, gx = bx + (p % 10) - 1;
            const ushort* src = zg;
            if (q < 8 && (unsigned)gy < 96u && (unsigned)gx < 96u)
                src = xin + ((size_t)(b * 9216 + gy * 96 + gx) * CIN
                             + sl * 64 + q * 8);
            GL_LDS16(src, s_act[buf] + (size_t)i * 8);
        }
    };

    STAGE(0, 0);
    __syncthreads();
#pragma unroll
    for (int sl = 0; sl < SL; ++sl) {
        if (sl + 1 < SL) STAGE(sl + 1, (sl + 1) & 1);
#pragma unroll
        for (int cc2 = 0; cc2 < 2; ++cc2) {
#pragma unroll
            for (int kk = 0; kk < 9; ++kk) {
                bf16x8 bfrag = *(const bf16x8*)(s_act[sl & (SL - 1)] + b_base +
                                   ((kk / 3) * 10 + (kk % 3)) * 72 + cc2 * 32);
#pragma unroll
                for (int mt = 0; mt < MT; ++mt) {
                    bf16x8 af = *(const bf16x8*)(wlane +
                        ((size_t)((sl * 2 + cc2) * 36 + kk * 4) * CoutP + mt * 16) * 8);
                    acc[mt] = __builtin_amdgcn_mfma_f32_16x16x32_bf16(
                        af, bfrag, acc[mt], 0, 0, 0);
                }
            }
        }
        if (sl + 1 < SL) __syncthreads();
    }

    int gy = by + py, gx = bx + pxx;
    size_t pxg = (size_t)b * 9216 + gy * 96 + gx;
#pragma unroll
    for (int mt = 0; mt < MT; ++mt) {
        int ocb = oc0 + mt * 16 + l4 * 4;
        ushort hb[4];
#pragma unroll
        for (int r = 0; r < 4; ++r) {
            int oc = ocb + r;
            float v = acc[mt][r] + ((oc < CoutR) ? bias[oc] : 0.f);
            if (LRELU) v = (v >= 0.f) ? v : 0.1f * v;
            hb[r] = f2bf(v);
            if (ST_F32 && oc < CoutR)
                outf[((size_t)b * CoutR + oc) * 9216 + gy * 96 + gx] = v;
        }
        if (ST_CHL && ocb < CoutR) {
            uint2 pk;
            pk.x = (uint)hb[0] | ((uint)hb[1] << 16);
            pk.y = (uint)hb[2] | ((uint)hb[3] << 16);
            *(uint2*)(chl + pxg * ochs + ocoff + ocb) = pk;
        }
    }
}

// ---------------------------------------------------------------------------
// Fused DCNv2 (f16 datapath): gather-layout xg1 [b][g][px][8] f16, wdp f16.
// Lerp via packed v_pk_fma_f16 (16 ops/step), MFMA f32_16x16x32_f16.
// split-K(2), interleaved om (bf16), distance-1 software-pipelined PREP.
// grid = 2304 x 128 thr.
__global__ __launch_bounds__(128, 4) void dcn_fused_k(
        const ushort* __restrict__ xg1,      // [b][8][9216][8] f16
        const ushort* __restrict__ om,       // [b][px][288] interleaved bf16
        const ushort* __restrict__ wdp,      // f16 [gkk*64+oc][8]
        const float* __restrict__ bd, ushort* __restrict__ chl) {
    __shared__ float s_red[64][17];
    int tid = threadIdx.x;
    int kq = tid >> 6, ln = tid & 63;
    int l15 = ln & 15, l4 = ln >> 4;
    int bid = blockIdx.x;                     // 0..2303
    int nid = (bid & 7) * 288 + (bid >> 3);   // XCD-chunked swizzle
    int pxb = nid % 576; int b = nid / 576;   // b-major banding
    int px = pxb * 16 + l15;
    int y = px / 96, xx = px % 96;

    f32x4 acc[4];
#pragma unroll
    for (int mt = 0; mt < 4; ++mt) acc[mt] = (f32x4){0.f, 0.f, 0.f, 0.f};
    const ushort* omp_ = om + ((size_t)b * 9216 + px) * 288 + kq * 144;

    // hoist the 9 om quads (oy,ox,ml,pad): one latency wait total
    uint2 ovv[9];
#pragma unroll
    for (int s = 0; s < 9; ++s)
        ovv[s] = *(const uint2*)(omp_ + s * 16 + l4 * 4);

    int4v Abuf[2][4];
    float cwbuf[2][4];

    auto PREP = [&](int s, int4v* A, float* cw) {
        int gkk = kq * 36 + s * 4 + l4;
        int g = gkk / 9, kk = gkk - g * 9;
        union { uint2 u; ushort us[4]; } ov; ov.u = ovv[s];
        float oy = bf2f(ov.us[0]), ox = bf2f(ov.us[1]);
        float mm = 1.f / (1.f + __expf(-bf2f(ov.us[2])));
        float py = oy + (float)(y + kk / 3 - 1);
        float pxf = ox + (float)(xx + kk % 3 - 1);
        float yf = floorf(py), xf = floorf(pxf);
        float fy = py - yf, fx = pxf - xf;
        int iy0 = (int)yf, ix0 = (int)xf;
        int iy1 = iy0 + 1, ix1 = ix0 + 1;
        float vy0 = ((unsigned)iy0 < 96u) ? 1.f : 0.f;
        float vy1 = ((unsigned)iy1 < 96u) ? 1.f : 0.f;
        float vx0 = ((unsigned)ix0 < 96u) ? 1.f : 0.f;
        float vx1 = ((unsigned)ix1 < 96u) ? 1.f : 0.f;
        int r0 = min(max(iy0, 0), 95), r1 = min(max(iy1, 0), 95);
        int lb = min(max(ix0, 0), 94);
        // half-selects: which 16B cell (lb or lb+1) each x-corner lives in
        float h0 = (float)min(max(ix0 - lb, 0), 1);   // 1 only when ix0==95
        float h1 = (float)min(max(ix1 - lb, 0), 1);   // 0 only when ix0==-1
        float wx0 = (1.f - fx) * vx0, wx1 = fx * vx1;
        float xw0 = wx0 * (1.f - h0) + wx1 * (1.f - h1);
        float xw1 = wx0 * h0 + wx1 * h1;
        float rw0 = (1.f - fy) * vy0 * mm, rw1 = fy * vy1 * mm;
        cw[0] = rw0 * xw0; cw[1] = rw0 * xw1;
        cw[2] = rw1 * xw0; cw[3] = rw1 * xw1;
        const ushort* gp = xg1 + ((size_t)(b * 8 + g) * 9216) * 8;
        const ushort* p0 = gp + ((size_t)(r0 * 96 + lb)) * 8;
        const ushort* p1 = gp + ((size_t)(r1 * 96 + lb)) * 8;
        A[0] = *(const int4v*)p0;
        A[1] = *(const int4v*)(p0 + 8);
        A[2] = *(const int4v*)p1;
        A[3] = *(const int4v*)(p1 + 8);
    };

    PREP(0, Abuf[0], cwbuf[0]);
#pragma unroll
    for (int s = 0; s < 9; ++s) {
        if (s + 1 < 9) PREP(s + 1, Abuf[(s + 1) & 1], cwbuf[(s + 1) & 1]);
        const int4v* A = Abuf[s & 1];
        const float* cw = cwbuf[s & 1];
        union { int4v v; __half2 h2[4]; } a0, a1, b0, b1;
        a0.v = A[0]; a1.v = A[1]; b0.v = A[2]; b1.v = A[3];
        __half2 w0 = __float2half2_rn(cw[0]);
        __half2 w1 = __float2half2_rn(cw[1]);
        __half2 w2 = __float2half2_rn(cw[2]);
        __half2 w3 = __float2half2_rn(cw[3]);
        union { __half2 h2[4]; half8 v; } bu;
#pragma unroll
        for (int j = 0; j < 4; ++j) {
            __half2 t = __hmul2(a0.h2[j], w0);
            t = __hfma2(a1.h2[j], w1, t);
            t = __hfma2(b0.h2[j], w2, t);
            t = __hfma2(b1.h2[j], w3, t);
            bu.h2[j] = t;
        }
        int gkk = kq * 36 + s * 4 + l4;
#pragma unroll
        for (int mt = 0; mt < 4; ++mt) {
            half8 af = *(const half8*)(wdp +
                ((size_t)gkk * 64 + mt * 16 + l15) * 8);
            acc[mt] = __builtin_amdgcn_mfma_f32_16x16x32_f16(
                af, bu.v, acc[mt], 0, 0, 0);
        }
    }

    // split-K reduce: kq=1 writes, kq=0 adds + stores
    if (kq) {
#pragma unroll
        for (int mt = 0; mt < 4; ++mt)
#pragma unroll
            for (int r = 0; r < 4; ++r)
                s_red[ln][mt * 4 + r] = acc[mt][r];
    }
    __syncthreads();
    if (!kq) {
        size_t pb = (size_t)b * 9216 + px;
#pragma unroll
        for (int mt = 0; mt < 4; ++mt) {
            ushort hb[4];
#pragma unroll
            for (int r = 0; r < 4; ++r) {
                int oc = mt * 16 + l4 * 4 + r;
                float v = acc[mt][r] + s_red[ln][mt * 4 + r] + bd[oc];
                hb[r] = f2bf(v);
            }
            uint2 pk;
            pk.x = (uint)hb[0] | ((uint)hb[1] << 16);
            pk.y = (uint)hb[2] | ((uint)hb[3] << 16);
            *(uint2*)(chl + pb * 128 + mt * 16 + l4 * 4) = pk;
        }
    }
}

// ---------------------------------------------------------------------------
extern "C" void kernel_launch(void* const* d_in, const int* in_sizes, int n_in,
                              void* d_out, int out_size, void* d_ws, size_t ws_size,
                              hipStream_t stream) {
    const float* src0  = (const float*)d_in[0];
    const float* src1  = (const float*)d_in[1];
    const float* l_off = (const float*)d_in[2];
    const float* l_fea = (const float*)d_in[3];
    const float* w1 = (const float*)d_in[4];   const float* b1 = (const float*)d_in[5];
    const float* w2 = (const float*)d_in[6];   const float* b2 = (const float*)d_in[7];
    const float* w3 = (const float*)d_in[8];   const float* b3 = (const float*)d_in[9];
    const float* wom = (const float*)d_in[10]; const float* bom = (const float*)d_in[11];
    const float* wd = (const float*)d_in[12];  const float* bd = (const float*)d_in[13];
    const float* wf = (const float*)d_in[14];  const float* bf = (const float*)d_in[15];

    // workspace schedule (lifetimes annotated; regions reused after death)
    char* W = (char*)d_ws;
    ushort* xin1 = (ushort*)(W + 0);          //  9,437,184 B  live to conv1
    ushort* xin2 = (ushort*)(W + 9437184);    //  9,437,184 B  dead after conv2
    ushort* xoff = (ushort*)(W + 9437184);    //  4,718,592 B  over xin2 (dead)
    ushort* xin3 = (ushort*)(W + 18874368);   //  4,718,592 B  dead after conv3
    ushort* omb  = (ushort*)(W + 23592960);   // 21,233,664 B  [b][px][288]
    ushort* xin4 = (ushort*)(W + 44826624);   //  9,437,184 B  [b][px][128]
    ushort* xg1  = (ushort*)(W + 54263808);   //  4,718,592 B  [b][8][px][8] f16
    ushort* w1p  = (ushort*)(W + 58982400);   // 147,456 B
    ushort* w2p  = (ushort*)(W + 59129856);   // 147,456 B
    ushort* w3p  = (ushort*)(W + 59277312);   //  73,728 B
    ushort* womp = (ushort*)(W + 59351040);   // 331,776 B (288-wide permuted)
    ushort* wdp  = (ushort*)(W + 59682816);   //  73,728 B (f16)
    ushort* wfp  = (ushort*)(W + 59756544);   // 147,456 B
    float*  bpp  = (float*)(W + 59904000);    //   1,152 B permuted om bias
    float*  zgrd = (float*)(W + 59905152);    //      64 B zero guard -> 57.1 MB

    float* out_off = (float*)d_out;
    float* out_fea = out_off + (size_t)4 * 64 * 9216;

    // fused packs + prepack (z=3)
    pack_combo_k<<<dim3(144, 4, 4), 256, 0, stream>>>(
        src0, src1, l_off, l_fea, w1, w2, w3, wom, wd, wf, bom,
        xin1, xin2, xin4, xg1, w1p, w2p, w3p, womp, wdp, wfp, bpp, zgrd);

    const ushort* zg = (const ushort*)zgrd;
    // conv1: xin1 -> xin2[0:64] (lrelu, ch-last)   [round-8 proven MT=2/NZ=2]
    conv_mfma_k<128, 2, 2, true, false, true><<<1152, 256, 0, stream>>>(
        xin1, w1p, b1, nullptr, xin2, zg, 64, 64, 128, 0);
    // conv2: xin2 -> xin3 (lrelu, ch-last)
    conv_mfma_k<128, 2, 2, true, false, true><<<1152, 256, 0, stream>>>(
        xin2, w2p, b2, nullptr, xin3, zg, 64, 64, 64, 0);
    // conv3: xin3 -> out_off (fp32 NCHW) + xoff (ch-last)
    conv_mfma_k<64, 2, 2, true, true, true><<<1152, 256, 0, stream>>>(
        xin3, w3p, b3, out_off, xoff, zg, 64, 64, 64, 0);
    // om conv: xoff -> omb interleaved [px][288], exact CoutP=288 (MT=6/NZ=3)
    conv_mfma_k<64, 6, 3, false, false, true><<<1728, 256, 0, stream>>>(
        xoff, womp, bpp, nullptr, omb, zg, 288, 288, 288, 0);
    // fused DCN -> xin4[0:64]  (samples xg1 f16, reads omb interleaved)
    dcn_fused_k<<<2304, 128, 0, stream>>>(xg1, omb, wdp, bd, xin4);
    // fea conv: xin4 -> out_fea (fp32 NCHW, lrelu)
    conv_mfma_k<128, 2, 2, true, true, false><<<1152, 256, 0, stream>>>(
        xin4, wfp, bf, out_fea, nullptr, zg, 64, 64, 0, 0);
}

// Round 11
// 131.765 us; speedup vs baseline: 1.1936x; 1.1015x over previous
//
#include <hip/hip_runtime.h>
#include <hip/hip_fp16.h>
#include <math.h>

typedef __attribute__((ext_vector_type(8))) short bf16x8;
typedef __attribute__((ext_vector_type(8))) _Float16 half8;
typedef __attribute__((ext_vector_type(4))) float f32x4;
typedef __attribute__((ext_vector_type(4))) int int4v;

#define GL_LDS16(g, l) __builtin_amdgcn_global_load_lds( \
    (const __attribute__((address_space(1))) void*)(g), \
    (__attribute__((address_space(3))) void*)(l), 16, 0, 0)

__device__ __forceinline__ ushort f2bf(float f) {
    union { float f; unsigned u; } v; v.f = f;
    unsigned r = (v.u + 0x7fffu + ((v.u >> 16) & 1u)) >> 16;
    return (ushort)r;
}
__device__ __forceinline__ float bf2f(ushort h) {
    union { unsigned u; float f; } v; v.u = ((unsigned)h) << 16;
    return v.f;
}

// ---------------------------------------------------------------------------
// Weight prepack helper: w[oc][cin][3][3] -> wp[cc][kk][kg][CoutP][8]
__device__ __forceinline__ void prep_one(const float* __restrict__ w,
        ushort* __restrict__ wp, int u, int Cin, int CoutR, int CoutP) {
    int oc = u % CoutP; int t = u / CoutP;
    int kg = t & 3; t >>= 2;
    int kk = t % 9; int cc = t / 9;
    alignas(16) ushort tmp[8];
    for (int j = 0; j < 8; ++j) {
        int c = cc * 32 + kg * 8 + j;
        float v = (oc < CoutR) ? w[((size_t)oc * Cin + c) * 9 + kk] : 0.f;
        tmp[j] = f2bf(v);
    }
    *(int4v*)(wp + (size_t)u * 8) = *(int4v*)tmp;
}

// ---------------------------------------------------------------------------
// Fused packs + prepack:
//  z=0: pack concat(src0,src1)->xin1[px][128] (bf16) AND xg1[b][g][px][8] (f16)
//  z=1: up2(l_off)*2 -> xin2[px][64:128]; z=2: up2(l_fea) -> xin4[px][64:128]
//  z=3: all weight prepacks (wd -> f16) + om bias permute + zero guard
__global__ __launch_bounds__(256) void pack_combo_k(
        const float* __restrict__ s0, const float* __restrict__ s1,
        const float* __restrict__ lo, const float* __restrict__ lf,
        const float* __restrict__ w1, const float* __restrict__ w2,
        const float* __restrict__ w3, const float* __restrict__ wom,
        const float* __restrict__ wd, const float* __restrict__ wf,
        const float* __restrict__ bom,
        ushort* __restrict__ xin1, ushort* __restrict__ xin2,
        ushort* __restrict__ xin4, ushort* __restrict__ xg1,
        ushort* __restrict__ w1p, ushort* __restrict__ w2p,
        ushort* __restrict__ w3p, ushort* __restrict__ womp,
        ushort* __restrict__ wdp, ushort* __restrict__ wfp,
        float* __restrict__ bpp, float* __restrict__ zg) {
    int b = blockIdx.y;
    int z = blockIdx.z;
    int px = blockIdx.x * 64 + (threadIdx.x & 63);
    int u = threadIdx.x >> 6;
    if (z == 0) {
        for (int half = 0; half < 2; ++half) {
            int cg = u + half * 4;
            float vals[16];
            alignas(16) ushort tmp[16];
            for (int i = 0; i < 16; ++i) {
                int c = cg * 16 + i;
                float v = (c < 64) ? s0[((size_t)(b * 64 + c)) * 9216 + px]
                                   : s1[((size_t)(b * 64 + c - 64)) * 9216 + px];
                vals[i] = v;
                tmp[i] = f2bf(v);
            }
            ushort* dst = xin1 + ((size_t)(b * 9216) + px) * 128 + cg * 16;
            *(int4v*)dst = *(int4v*)&tmp[0];
            *(int4v*)(dst + 8) = *(int4v*)&tmp[8];
            if (half == 0) {
                // gather copy in f16: groups g = cg*2, cg*2+1
                alignas(16) __half th[16];
                for (int i = 0; i < 16; ++i) th[i] = __float2half(vals[i]);
                ushort* gdst = xg1 + (((size_t)(b * 8 + cg * 2) * 9216) + px) * 8;
                *(int4v*)gdst = *(int4v*)&th[0];
                *(int4v*)(gdst + 9216 * 8) = *(int4v*)&th[8];
            }
        }
    } else if (z < 3) {
        const float* in = (z == 1) ? lo : lf;
        float scale = (z == 1) ? 2.0f : 1.0f;
        ushort* xo = (z == 1) ? xin2 : xin4;
        int y = px / 96, x = px % 96;
        float sy = fmaxf(y * 0.5f - 0.25f, 0.f);
        float sx = fmaxf(x * 0.5f - 0.25f, 0.f);
        int y0 = (int)sy, x0 = (int)sx;
        float ty = sy - (float)y0, tx = sx - (float)x0;
        int y1 = min(y0 + 1, 47), x1 = min(x0 + 1, 47);
        alignas(16) ushort tmp[16];
        for (int i = 0; i < 16; ++i) {
            int c = u * 16 + i;
            const float* p = in + ((size_t)(b * 64 + c)) * 2304;
            float v00 = p[y0 * 48 + x0], v01 = p[y0 * 48 + x1];
            float v10 = p[y1 * 48 + x0], v11 = p[y1 * 48 + x1];
            float v = (v00 * (1.f - tx) + v01 * tx) * (1.f - ty)
                    + (v10 * (1.f - tx) + v11 * tx) * ty;
            tmp[i] = f2bf(v * scale);
        }
        ushort* dst = xo + ((size_t)(b * 9216) + px) * 128 + 64 + u * 16;
        *(int4v*)dst = *(int4v*)&tmp[0];
        *(int4v*)(dst + 8) = *(int4v*)&tmp[8];
    } else {
        // prepack: 57904 units over 576 blocks
        int uu = (blockIdx.x + 144 * blockIdx.y) * 256 + threadIdx.x;
        if (uu < 9216) prep_one(w1, w1p, uu, 128, 64, 64);
        else if (uu < 18432) prep_one(w2, w2p, uu - 9216, 128, 64, 64);
        else if (uu < 23040) prep_one(w3, w3p, uu - 18432, 64, 64, 64);
        else if (uu < 43776) {
            // om conv, permuted: CoutP=288, oc p = gkk*4 + t3 (t3==3 -> pad)
            int v = uu - 23040;               // units = 2*9*4*288 = 20736
            int ocp = v % 288; int t = v / 288;
            int kg = t & 3; t >>= 2;
            int kk = t % 9; int cc = t / 9;
            int t3 = ocp & 3, gkkp = ocp >> 2;
            alignas(16) ushort tmp[8];
            for (int j = 0; j < 8; ++j) {
                int c = cc * 32 + kg * 8 + j;
                float vv = (t3 < 3)
                    ? wom[((size_t)(t3 * 72 + gkkp) * 64 + c) * 9 + kk] : 0.f;
                tmp[j] = f2bf(vv);
            }
            *(int4v*)(womp + (size_t)v * 8) = *(int4v*)tmp;
        } else if (uu < 48384) {
            int v = uu - 43776;               // wd -> f16 [gkk*64 + oc][8]
            int oc = v & 63; int gkk = v >> 6;
            int g = gkk / 9, kk = gkk % 9;
            alignas(16) __half tmp[8];
            for (int j = 0; j < 8; ++j)
                tmp[j] = __float2half(wd[((size_t)oc * 64 + g * 8 + j) * 9 + kk]);
            *(int4v*)(wdp + (size_t)v * 8) = *(int4v*)tmp;
        } else if (uu < 57600) prep_one(wf, wfp, uu - 48384, 128, 64, 64);
        else if (uu < 57888) {
            int ocp = uu - 57600; int t3 = ocp & 3, gkkp = ocp >> 2;
            bpp[ocp] = (t3 < 3) ? bom[t3 * 72 + gkkp] : 0.f;
        } else if (uu < 57904) zg[uu - 57888] = 0.f;  // 64-B zero guard
    }
}

// ---------------------------------------------------------------------------
// MFMA 3x3 conv: per-wave MT*16 oc x 16 px, block = 8x8 px tile.
// Activation staged in 64-channel slices via global_load_lds; zero-guard for
// pad/OOB. CIN=64: single stage (one barrier). CIN=128: 2 slices dbuf.
// A-fragments read directly from global prepacked weights (L1-hot).
template<int CIN, int MT, int NZ, bool LRELU, bool ST_F32, bool ST_CHL>
__global__ __launch_bounds__(256, 4) void conv_mfma_k(
        const ushort* __restrict__ xin,      // [b][9216][CIN] bf16
        const ushort* __restrict__ wp,       // [CIN/32][9][4][CoutP][8]
        const float* __restrict__ bias,
        float* __restrict__ outf,            // NCHW fp32
        ushort* __restrict__ chl,            // ch-last bf16
        const ushort* __restrict__ zg,       // 64-B zero guard
        int CoutR, int CoutP, int ochs, int ocoff) {
    constexpr int SL = CIN / 64;
    constexpr int OCN = MT * 16;
    __shared__ ushort s_act[SL][7200];        // [buf][100 rows x 72u] 14.4 KB each

    int tid = threadIdx.x;
    int wv = tid >> 6, ln = tid & 63;
    int l15 = ln & 15, l4 = ln >> 4;

    constexpr int TOTAL = 144 * 4 * NZ;
    constexpr int CHUNK = TOTAL / 8;
    int bid = blockIdx.x;
    int nid = (bid & 7) * CHUNK + (bid >> 3);
    int zc = nid % NZ; int r1 = nid / NZ;
    int tile = r1 % 144; int b = r1 / 144;    // b-major banding
    int bx = (tile % 12) * 8, by = (tile / 12) * 8;
    int oc0 = zc * OCN;

    int px_l = wv * 16 + l15;                 // px in 8x8 tile
    int py = px_l >> 3, pxx = px_l & 7;
    int b_base = (py * 10 + pxx) * 72 + l4 * 8;

    const ushort* wlane = wp + ((size_t)l4 * CoutP + oc0 + l15) * 8;

    f32x4 acc[MT];
#pragma unroll
    for (int mt = 0; mt < MT; ++mt) acc[mt] = (f32x4){0.f, 0.f, 0.f, 0.f};

    auto STAGE = [&](int sl, int buf) {
        for (int i = tid; i < 900; i += 256) {
            int p = i / 9, q = i - p * 9;     // q==8 -> pad slot
            int gy = by + (p / 10) - 1, gx = bx + (p % 10) - 1;
            const ushort* src = zg;
            if (q < 8 && (unsigned)gy < 96u && (unsigned)gx < 96u)
                src = xin + ((size_t)(b * 9216 + gy * 96 + gx) * CIN
                             + sl * 64 + q * 8);
            GL_LDS16(src, s_act[buf] + (size_t)i * 8);
        }
    };

    STAGE(0, 0);
    __syncthreads();
#pragma unroll
    for (int sl = 0; sl < SL; ++sl) {
        if (sl + 1 < SL) STAGE(sl + 1, (sl + 1) & 1);
#pragma unroll
        for (int cc2 = 0; cc2 < 2; ++cc2) {
#pragma unroll
            for (int kk = 0; kk < 9; ++kk) {
                bf16x8 bfrag = *(const bf16x8*)(s_act[sl & (SL - 1)] + b_base +
                                   ((kk / 3) * 10 + (kk % 3)) * 72 + cc2 * 32);
#pragma unroll
                for (int mt = 0; mt < MT; ++mt) {
                    bf16x8 af = *(const bf16x8*)(wlane +
                        ((size_t)((sl * 2 + cc2) * 36 + kk * 4) * CoutP + mt * 16) * 8);
                    acc[mt] = __builtin_amdgcn_mfma_f32_16x16x32_bf16(
                        af, bfrag, acc[mt], 0, 0, 0);
                }
            }
        }
        if (sl + 1 < SL) __syncthreads();
    }

    int gy = by + py, gx = bx + pxx;
    size_t pxg = (size_t)b * 9216 + gy * 96 + gx;
#pragma unroll
    for (int mt = 0; mt < MT; ++mt) {
        int ocb = oc0 + mt * 16 + l4 * 4;
        ushort hb[4];
#pragma unroll
        for (int r = 0; r < 4; ++r) {
            int oc = ocb + r;
            float v = acc[mt][r] + ((oc < CoutR) ? bias[oc] : 0.f);
            if (LRELU) v = (v >= 0.f) ? v : 0.1f * v;
            hb[r] = f2bf(v);
            if (ST_F32 && oc < CoutR)
                outf[((size_t)b * CoutR + oc) * 9216 + gy * 96 + gx] = v;
        }
        if (ST_CHL && ocb < CoutR) {
            uint2 pk;
            pk.x = (uint)hb[0] | ((uint)hb[1] << 16);
            pk.y = (uint)hb[2] | ((uint)hb[3] << 16);
            *(uint2*)(chl + pxg * ochs + ocoff + ocb) = pk;
        }
    }
}

// ---------------------------------------------------------------------------
// Fused om-conv + DCNv2. Block = 128 thr = 2 waves (kq = K-half), 16 px band.
// Phase 1: stage xoff halo band (3 rows x 18 cols x 64 ch) with chunk-XOR
//   swizzle (both sides), then compute om IN-REGISTER via MFMA: wave kq's
//   aom[s] C-fragment holds exactly om quad (oy,ox,ml,pad) for
//   gkk = kq*36 + s*4 + l4 at px = l15 — the permuted layout IS the C layout.
// Phase 2: existing f16 sampling pipeline consumes aom[s] from registers.
// grid = 2304 x 128 thr.
__global__ __launch_bounds__(128, 3) void dcn_fused_k(
        const ushort* __restrict__ xoff,     // [b][px][64] ch-last bf16
        const ushort* __restrict__ xg1,      // [b][8][9216][8] f16
        const ushort* __restrict__ womp,     // [cc][kk][4][288][8] bf16
        const float* __restrict__ bpp,       // permuted om bias [288]
        const ushort* __restrict__ wdp,      // f16 [gkk*64+oc][8]
        const float* __restrict__ bd, ushort* __restrict__ chl,
        const ushort* __restrict__ zg) {
    __shared__ ushort s_x[3456];              // 432 chunks x 16 B = 6912 B
    __shared__ float s_red[64][17];
    int tid = threadIdx.x;
    int kq = tid >> 6, ln = tid & 63;
    int l15 = ln & 15, l4 = ln >> 4;
    int bid = blockIdx.x;                     // 0..2303
    int nid = (bid & 7) * 288 + (bid >> 3);   // XCD-chunked swizzle
    int pxb = nid % 576; int b = nid / 576;   // b-major banding
    int px0 = pxb * 16;
    int px = px0 + l15;
    int y = px0 / 96, x0 = px0 % 96;
    int xx = x0 + l15;

    // ---- phase 1: stage xoff halo band (rows y-1..y+1, cols x0-1..x0+16) ----
    for (int i = tid; i < 432; i += 128) {
        int P = i >> 3, s8 = i & 7;
        int q = s8 ^ (P & 7);                 // inverse-swizzled source chunk
        int ry = y - 1 + P / 18, rx = x0 - 1 + P % 18;
        const ushort* src = zg;
        if ((unsigned)ry < 96u && (unsigned)rx < 96u)
            src = xoff + (((size_t)b * 9216 + ry * 96 + rx) * 64 + q * 8);
        GL_LDS16(src, s_x + (size_t)i * 8);
    }
    __syncthreads();

    // in-register om conv: aom[s] accumulates oc-tile s of wave kq's 144-oc half
    f32x4 aom[9];
#pragma unroll
    for (int s = 0; s < 9; ++s) aom[s] = (f32x4){0.f, 0.f, 0.f, 0.f};
#pragma unroll
    for (int kk = 0; kk < 9; ++kk) {
        int ky = kk / 3, kx = kk % 3;
#pragma unroll
        for (int cc = 0; cc < 2; ++cc) {
            int P = ky * 18 + l15 + kx;
            int c8 = cc * 4 + l4;
            bf16x8 bfrag = *(const bf16x8*)(s_x +
                ((size_t)(P * 8 + (c8 ^ (P & 7)))) * 8);
#pragma unroll
            for (int s = 0; s < 9; ++s) {
                bf16x8 af = *(const bf16x8*)(womp +
                    ((size_t)(((cc * 9 + kk) * 4 + l4) * 288)
                     + kq * 144 + s * 16 + l15) * 8);
                aom[s] = __builtin_amdgcn_mfma_f32_16x16x32_bf16(
                    af, bfrag, aom[s], 0, 0, 0);
            }
        }
    }

    // ---- phase 2: sampling + PV MFMA (f16 datapath) ----
    f32x4 acc[4];
#pragma unroll
    for (int mt = 0; mt < 4; ++mt) acc[mt] = (f32x4){0.f, 0.f, 0.f, 0.f};

    int4v Abuf[2][4];
    float cwbuf[2][4];

    auto PREP = [&](int s, int4v* A, float* cw) {
        int gkk = kq * 36 + s * 4 + l4;
        int g = gkk / 9, kk = gkk - g * 9;
        int bofs = kq * 144 + s * 16 + l4 * 4;
        float oy = aom[s][0] + bpp[bofs];
        float ox = aom[s][1] + bpp[bofs + 1];
        float mm = 1.f / (1.f + __expf(-(aom[s][2] + bpp[bofs + 2])));
        float py = oy + (float)(y + kk / 3 - 1);
        float pxf = ox + (float)(xx + kk % 3 - 1);
        float yf = floorf(py), xf = floorf(pxf);
        float fy = py - yf, fx = pxf - xf;
        int iy0 = (int)yf, ix0 = (int)xf;
        int iy1 = iy0 + 1, ix1 = ix0 + 1;
        float vy0 = ((unsigned)iy0 < 96u) ? 1.f : 0.f;
        float vy1 = ((unsigned)iy1 < 96u) ? 1.f : 0.f;
        float vx0 = ((unsigned)ix0 < 96u) ? 1.f : 0.f;
        float vx1 = ((unsigned)ix1 < 96u) ? 1.f : 0.f;
        int r0 = min(max(iy0, 0), 95), r1 = min(max(iy1, 0), 95);
        int lb = min(max(ix0, 0), 94);
        // half-selects: which 16B cell (lb or lb+1) each x-corner lives in
        float h0 = (float)min(max(ix0 - lb, 0), 1);   // 1 only when ix0==95
        float h1 = (float)min(max(ix1 - lb, 0), 1);   // 0 only when ix0==-1
        float wx0 = (1.f - fx) * vx0, wx1 = fx * vx1;
        float xw0 = wx0 * (1.f - h0) + wx1 * (1.f - h1);
        float xw1 = wx0 * h0 + wx1 * h1;
        float rw0 = (1.f - fy) * vy0 * mm, rw1 = fy * vy1 * mm;
        cw[0] = rw0 * xw0; cw[1] = rw0 * xw1;
        cw[2] = rw1 * xw0; cw[3] = rw1 * xw1;
        const ushort* gp = xg1 + ((size_t)(b * 8 + g) * 9216) * 8;
        const ushort* p0 = gp + ((size_t)(r0 * 96 + lb)) * 8;
        const ushort* p1 = gp + ((size_t)(r1 * 96 + lb)) * 8;
        A[0] = *(const int4v*)p0;
        A[1] = *(const int4v*)(p0 + 8);
        A[2] = *(const int4v*)p1;
        A[3] = *(const int4v*)(p1 + 8);
    };

    PREP(0, Abuf[0], cwbuf[0]);
#pragma unroll
    for (int s = 0; s < 9; ++s) {
        if (s + 1 < 9) PREP(s + 1, Abuf[(s + 1) & 1], cwbuf[(s + 1) & 1]);
        const int4v* A = Abuf[s & 1];
        const float* cw = cwbuf[s & 1];
        union { int4v v; __half2 h2[4]; } a0, a1, b0, b1;
        a0.v = A[0]; a1.v = A[1]; b0.v = A[2]; b1.v = A[3];
        __half2 w0 = __float2half2_rn(cw[0]);
        __half2 w1 = __float2half2_rn(cw[1]);
        __half2 w2 = __float2half2_rn(cw[2]);
        __half2 w3 = __float2half2_rn(cw[3]);
        union { __half2 h2[4]; half8 v; } bu;
#pragma unroll
        for (int j = 0; j < 4; ++j) {
            __half2 t = __hmul2(a0.h2[j], w0);
            t = __hfma2(a1.h2[j], w1, t);
            t = __hfma2(b0.h2[j], w2, t);
            t = __hfma2(b1.h2[j], w3, t);
            bu.h2[j] = t;
        }
        int gkk = kq * 36 + s * 4 + l4;
#pragma unroll
        for (int mt = 0; mt < 4; ++mt) {
            half8 af = *(const half8*)(wdp +
                ((size_t)gkk * 64 + mt * 16 + l15) * 8);
            acc[mt] = __builtin_amdgcn_mfma_f32_16x16x32_f16(
                af, bu.v, acc[mt], 0, 0, 0);
        }
    }

    // split-K reduce: kq=1 writes, kq=0 adds + stores
    if (kq) {
#pragma unroll
        for (int mt = 0; mt < 4; ++mt)
#pragma unroll
            for (int r = 0; r < 4; ++r)
                s_red[ln][mt * 4 + r] = acc[mt][r];
    }
    __syncthreads();
    if (!kq) {
        size_t pb = (size_t)b * 9216 + px;
#pragma unroll
        for (int mt = 0; mt < 4; ++mt) {
            ushort hb[4];
#pragma unroll
            for (int r = 0; r < 4; ++r) {
                int oc = mt * 16 + l4 * 4 + r;
                float v = acc[mt][r] + s_red[ln][mt * 4 + r] + bd[oc];
                hb[r] = f2bf(v);
            }
            uint2 pk;
            pk.x = (uint)hb[0] | ((uint)hb[1] << 16);
            pk.y = (uint)hb[2] | ((uint)hb[3] << 16);
            *(uint2*)(chl + pb * 128 + mt * 16 + l4 * 4) = pk;
        }
    }
}

// ---------------------------------------------------------------------------
extern "C" void kernel_launch(void* const* d_in, const int* in_sizes, int n_in,
                              void* d_out, int out_size, void* d_ws, size_t ws_size,
                              hipStream_t stream) {
    const float* src0  = (const float*)d_in[0];
    const float* src1  = (const float*)d_in[1];
    const float* l_off = (const float*)d_in[2];
    const float* l_fea = (const float*)d_in[3];
    const float* w1 = (const float*)d_in[4];   const float* b1 = (const float*)d_in[5];
    const float* w2 = (const float*)d_in[6];   const float* b2 = (const float*)d_in[7];
    const float* w3 = (const float*)d_in[8];   const float* b3 = (const float*)d_in[9];
    const float* wom = (const float*)d_in[10]; const float* bom = (const float*)d_in[11];
    const float* wd = (const float*)d_in[12];  const float* bd = (const float*)d_in[13];
    const float* wf = (const float*)d_in[14];  const float* bf = (const float*)d_in[15];

    // workspace schedule (lifetimes annotated; omb region now unused)
    char* W = (char*)d_ws;
    ushort* xin1 = (ushort*)(W + 0);          //  9,437,184 B  live to conv1
    ushort* xin2 = (ushort*)(W + 9437184);    //  9,437,184 B  dead after conv2
    ushort* xoff = (ushort*)(W + 9437184);    //  4,718,592 B  over xin2; live to dcn
    ushort* xin3 = (ushort*)(W + 18874368);   //  4,718,592 B  dead after conv3
    ushort* xin4 = (ushort*)(W + 44826624);   //  9,437,184 B  [b][px][128]
    ushort* xg1  = (ushort*)(W + 54263808);   //  4,718,592 B  [b][8][px][8] f16
    ushort* w1p  = (ushort*)(W + 58982400);   // 147,456 B
    ushort* w2p  = (ushort*)(W + 59129856);   // 147,456 B
    ushort* w3p  = (ushort*)(W + 59277312);   //  73,728 B
    ushort* womp = (ushort*)(W + 59351040);   // 331,776 B (288-wide permuted)
    ushort* wdp  = (ushort*)(W + 59682816);   //  73,728 B (f16)
    ushort* wfp  = (ushort*)(W + 59756544);   // 147,456 B
    float*  bpp  = (float*)(W + 59904000);    //   1,152 B permuted om bias
    float*  zgrd = (float*)(W + 59905152);    //      64 B zero guard

    float* out_off = (float*)d_out;
    float* out_fea = out_off + (size_t)4 * 64 * 9216;

    // fused packs + prepack (z=3)
    pack_combo_k<<<dim3(144, 4, 4), 256, 0, stream>>>(
        src0, src1, l_off, l_fea, w1, w2, w3, wom, wd, wf, bom,
        xin1, xin2, xin4, xg1, w1p, w2p, w3p, womp, wdp, wfp, bpp, zgrd);

    const ushort* zg = (const ushort*)zgrd;
    // conv1: xin1 -> xin2[0:64] (lrelu, ch-last)
    conv_mfma_k<128, 2, 2, true, false, true><<<1152, 256, 0, stream>>>(
        xin1, w1p, b1, nullptr, xin2, zg, 64, 64, 128, 0);
    // conv2: xin2 -> xin3 (lrelu, ch-last)
    conv_mfma_k<128, 2, 2, true, false, true><<<1152, 256, 0, stream>>>(
        xin2, w2p, b2, nullptr, xin3, zg, 64, 64, 64, 0);
    // conv3: xin3 -> out_off (fp32 NCHW) + xoff (ch-last)
    conv_mfma_k<64, 2, 2, true, true, true><<<1152, 256, 0, stream>>>(
        xin3, w3p, b3, out_off, xoff, zg, 64, 64, 64, 0);
    // fused om-conv + DCN -> xin4[0:64]
    dcn_fused_k<<<2304, 128, 0, stream>>>(xoff, xg1, womp, bpp, wdp, bd,
                                          xin4, zg);
    // fea conv: xin4 -> out_fea (fp32 NCHW, lrelu)
    conv_mfma_k<128, 2, 2, true, true, false><<<1152, 256, 0, stream>>>(
        xin4, wfp, bf, out_fea, nullptr, zg, 64, 64, 0, 0);
}